// Round 4
// baseline (421.110 us; speedup 1.0000x reference)
//
#include <hip/hip_runtime.h>
#include <math.h>

// Problem: B=64, R=20, L=1024, D=2048 fp32.  out[b,l] = max_r <region[b,r,:], word[b,l,:]>
// Memory-bound: 548 MB mandatory -> ~87us @ 6.3TB/s achievable.
//
// Structure (round-2 topology + async double-buffered staging):
//  - 4 waves/block, each wave owns 4 words and ALL 20 regions (words read once).
//  - regions staged in LDS, 2 x 20KB double buffer, async global_load_lds;
//    stage(c+1) issued right after the single per-chunk barrier so its latency
//    hides under chunk c's FMA+ds_read work.
//  - __launch_bounds__(256,4): VGPR cap 128 (acc 80 + wv 16 + addr fits, no spill).
#define BATCH 64
#define NREG  20
#define LWORDS 1024
#define DDIM  2048
#define DK    256                   // D-chunk: 20*256*4B = 20 KB per buffer
#define NCHUNK (DDIM / DK)          // 8
#define NWAVE 4
#define TPB   (NWAVE * 64)          // 256
#define WPW   4                     // words per wave
#define WORDS_PER_BLOCK (NWAVE * WPW)   // 16

// async global->LDS, 16B per lane; dst must be wave-uniform (HW adds lane*16)
__device__ __forceinline__ void gload_lds16(const float* src, float* dst) {
    __builtin_amdgcn_global_load_lds(
        (const __attribute__((address_space(1))) void*)src,
        (__attribute__((address_space(3))) void*)dst,
        16, 0, 0);
}

// DPP full-wave (64-lane) sum; result valid in lane 63.
template <int CTRL>
__device__ __forceinline__ float dpp_add_f32(float v) {
    int s = __builtin_amdgcn_update_dpp(0, __float_as_int(v), CTRL, 0xf, 0xf, true);
    return v + __int_as_float(s);
}
__device__ __forceinline__ float wave_sum64(float v) {
    v = dpp_add_f32<0x111>(v);  // row_shr:1
    v = dpp_add_f32<0x112>(v);  // row_shr:2
    v = dpp_add_f32<0x114>(v);  // row_shr:4
    v = dpp_add_f32<0x118>(v);  // row_shr:8
    v = dpp_add_f32<0x142>(v);  // row_bcast:15
    v = dpp_add_f32<0x143>(v);  // row_bcast:31 -> lane 63 = total
    return v;
}

__global__ __launch_bounds__(TPB, 4)
void score_max_kernel(const float* __restrict__ in0,   // (B*20, D) regions
                      const float* __restrict__ in1,   // (B, L, D) words
                      float* __restrict__ out) {       // (B, 1, L)
    __shared__ float reg_lds[2][NREG * DK];            // exactly 40 KB -> 4 blocks/CU

    const int bid  = blockIdx.x;
    // bid = t*64 + b: batch b always lands on XCD (b%8) -> regions L2-resident.
    const int b    = bid & 63;
    const int t    = bid >> 6;
    const int tid  = threadIdx.x;
    const int wave = tid >> 6;
    const int lane = tid & 63;
    const int l0   = t * WORDS_PER_BLOCK + wave * WPW;

    const float* regbase = in0 + (size_t)b * NREG * DDIM;
    const float* wordp   = in1 + ((size_t)b * LWORDS + l0) * DDIM + lane * 4;

    // stage regions[0..19][c*DK .. +DK) into reg_lds[bufsel] (async, 5 rows/wave)
    auto stage = [&](int bufsel, int c) {
        #pragma unroll
        for (int i = 0; i < NREG / NWAVE; ++i) {        // 5 rows per wave
            const int r = i * NWAVE + wave;              // wave-uniform row
            gload_lds16(regbase + (size_t)r * DDIM + c * DK + lane * 4,
                        &reg_lds[bufsel][r * DK]);
        }
    };

    float acc[NREG][WPW];
    #pragma unroll
    for (int r = 0; r < NREG; ++r)
        #pragma unroll
        for (int w = 0; w < WPW; ++w) acc[r][w] = 0.0f;

    stage(0, 0);
    int buf = 0;
    for (int c = 0; c < NCHUNK; ++c) {
        // barrier: implicit vmcnt(0) drain -> reg_lds[buf] fully staged; also
        // guarantees all waves finished reading reg_lds[buf^1] (chunk c-1).
        __syncthreads();
        if (c + 1 < NCHUNK) stage(buf ^ 1, c + 1);   // hides under compute below

        float4 wv[WPW];
        #pragma unroll
        for (int w = 0; w < WPW; ++w)
            wv[w] = *reinterpret_cast<const float4*>(wordp + (size_t)w * DDIM + c * DK);

        const float* rbase = &reg_lds[buf][lane * 4];
        #pragma unroll
        for (int r = 0; r < NREG; ++r) {
            const float4 rv = *reinterpret_cast<const float4*>(rbase + r * DK);
            #pragma unroll
            for (int w = 0; w < WPW; ++w) {
                float a = acc[r][w];
                a = fmaf(rv.x, wv[w].x, a);
                a = fmaf(rv.y, wv[w].y, a);
                a = fmaf(rv.z, wv[w].z, a);
                a = fmaf(rv.w, wv[w].w, a);
                acc[r][w] = a;
            }
        }
        buf ^= 1;
    }

    // epilogue: DPP wave-sum each acc, max over regions, lane 63 stores.
    #pragma unroll
    for (int w = 0; w < WPW; ++w) {
        float m = -INFINITY;
        #pragma unroll
        for (int r = 0; r < NREG; ++r)
            m = fmaxf(m, wave_sum64(acc[r][w]));
        if (lane == 63) out[(size_t)b * LWORDS + l0 + w] = m;
    }
}

extern "C" void kernel_launch(void* const* d_in, const int* in_sizes, int n_in,
                              void* d_out, int out_size, void* d_ws, size_t ws_size,
                              hipStream_t stream) {
    const float* in0 = (const float*)d_in[0];   // (B*20, D)
    const float* in1 = (const float*)d_in[1];   // (B, L, D)
    float* out = (float*)d_out;                  // (B, 1, L)

    const int grid = BATCH * (LWORDS / WORDS_PER_BLOCK);   // 64 * 64 = 4096
    score_max_kernel<<<grid, TPB, 0, stream>>>(in0, in1, out);
}

// Round 5
// 143.409 us; speedup vs baseline: 2.9364x; 2.9364x over previous
//
#include <hip/hip_runtime.h>
#include <math.h>

// Problem: B=64, R=20, L=1024, D=2048 fp32.  out[b,l] = max_r <region[b,r,:], word[b,l,:]>
// Memory-bound: 548 MB mandatory -> ~87us @ 6.5TB/s achievable.
//
// Structure:
//  - 4 waves/block, each wave owns 4 words and ALL 20 regions (words read once).
//  - regions staged in LDS, 2 x 20KB double buffer, async global_load_lds;
//    stage(c+1) issued right after the single per-chunk barrier so its latency
//    hides under chunk c's FMA+ds_read work.
//  - NO min-waves launch bound: rounds 3/4 proved capping VGPRs spills the
//    80-reg accumulator to scratch (+1.3 GB HBM).  acc must live in VGPRs.
#define BATCH 64
#define NREG  20
#define LWORDS 1024
#define DDIM  2048
#define DK    256                   // D-chunk: 20*256*4B = 20 KB per buffer
#define NCHUNK (DDIM / DK)          // 8
#define NWAVE 4
#define TPB   (NWAVE * 64)          // 256
#define WPW   4                     // words per wave
#define WORDS_PER_BLOCK (NWAVE * WPW)   // 16

// async global->LDS, 16B per lane; dst must be wave-uniform (HW adds lane*16)
__device__ __forceinline__ void gload_lds16(const float* src, float* dst) {
    __builtin_amdgcn_global_load_lds(
        (const __attribute__((address_space(1))) void*)src,
        (__attribute__((address_space(3))) void*)dst,
        16, 0, 0);
}

// DPP full-wave (64-lane) sum; result valid in lane 63.
template <int CTRL>
__device__ __forceinline__ float dpp_add_f32(float v) {
    int s = __builtin_amdgcn_update_dpp(0, __float_as_int(v), CTRL, 0xf, 0xf, true);
    return v + __int_as_float(s);
}
__device__ __forceinline__ float wave_sum64(float v) {
    v = dpp_add_f32<0x111>(v);  // row_shr:1
    v = dpp_add_f32<0x112>(v);  // row_shr:2
    v = dpp_add_f32<0x114>(v);  // row_shr:4
    v = dpp_add_f32<0x118>(v);  // row_shr:8
    v = dpp_add_f32<0x142>(v);  // row_bcast:15
    v = dpp_add_f32<0x143>(v);  // row_bcast:31 -> lane 63 = total
    return v;
}

__global__ __launch_bounds__(TPB)
void score_max_kernel(const float* __restrict__ in0,   // (B*20, D) regions
                      const float* __restrict__ in1,   // (B, L, D) words
                      float* __restrict__ out) {       // (B, 1, L)
    __shared__ float reg_lds[2][NREG * DK];            // 40 KB double buffer

    const int bid  = blockIdx.x;
    // bid = t*64 + b: batch b always lands on XCD (b%8) -> regions L2-resident.
    const int b    = bid & 63;
    const int t    = bid >> 6;
    const int tid  = threadIdx.x;
    const int wave = tid >> 6;
    const int lane = tid & 63;
    const int l0   = t * WORDS_PER_BLOCK + wave * WPW;

    const float* regbase = in0 + (size_t)b * NREG * DDIM;
    const float* wordp   = in1 + ((size_t)b * LWORDS + l0) * DDIM + lane * 4;

    // stage regions[0..19][c*DK .. +DK) into reg_lds[bufsel] (async, 5 rows/wave)
    auto stage = [&](int bufsel, int c) {
        #pragma unroll
        for (int i = 0; i < NREG / NWAVE; ++i) {        // 5 rows per wave
            const int r = i * NWAVE + wave;              // wave-uniform row
            gload_lds16(regbase + (size_t)r * DDIM + c * DK + lane * 4,
                        &reg_lds[bufsel][r * DK]);
        }
    };

    float acc[NREG][WPW];
    #pragma unroll
    for (int r = 0; r < NREG; ++r)
        #pragma unroll
        for (int w = 0; w < WPW; ++w) acc[r][w] = 0.0f;

    stage(0, 0);
    int buf = 0;
    for (int c = 0; c < NCHUNK; ++c) {
        // barrier: implicit vmcnt(0) drain -> reg_lds[buf] fully staged; also
        // guarantees all waves finished reading reg_lds[buf^1] (chunk c-1).
        __syncthreads();
        if (c + 1 < NCHUNK) stage(buf ^ 1, c + 1);   // hides under compute below

        float4 wv[WPW];
        #pragma unroll
        for (int w = 0; w < WPW; ++w)
            wv[w] = *reinterpret_cast<const float4*>(wordp + (size_t)w * DDIM + c * DK);

        const float* rbase = &reg_lds[buf][lane * 4];
        #pragma unroll
        for (int r = 0; r < NREG; ++r) {
            const float4 rv = *reinterpret_cast<const float4*>(rbase + r * DK);
            #pragma unroll
            for (int w = 0; w < WPW; ++w) {
                float a = acc[r][w];
                a = fmaf(rv.x, wv[w].x, a);
                a = fmaf(rv.y, wv[w].y, a);
                a = fmaf(rv.z, wv[w].z, a);
                a = fmaf(rv.w, wv[w].w, a);
                acc[r][w] = a;
            }
        }
        buf ^= 1;
    }

    // epilogue: DPP wave-sum each acc, max over regions, lane 63 stores.
    #pragma unroll
    for (int w = 0; w < WPW; ++w) {
        float m = -INFINITY;
        #pragma unroll
        for (int r = 0; r < NREG; ++r)
            m = fmaxf(m, wave_sum64(acc[r][w]));
        if (lane == 63) out[(size_t)b * LWORDS + l0 + w] = m;
    }
}

extern "C" void kernel_launch(void* const* d_in, const int* in_sizes, int n_in,
                              void* d_out, int out_size, void* d_ws, size_t ws_size,
                              hipStream_t stream) {
    const float* in0 = (const float*)d_in[0];   // (B*20, D)
    const float* in1 = (const float*)d_in[1];   // (B, L, D)
    float* out = (float*)d_out;                  // (B, 1, L)

    const int grid = BATCH * (LWORDS / WORDS_PER_BLOCK);   // 64 * 64 = 4096
    score_max_kernel<<<grid, TPB, 0, stream>>>(in0, in1, out);
}